// Round 1
// baseline (1042.744 us; speedup 1.0000x reference)
//
#include <hip/hip_runtime.h>
#include <cstdint>
#include <cstddef>

#define B   32
#define N   4096
#define NP  512
#define NS  16
#define C   256
#define CIN 259
#define HID 128
#define SB  (NP*NS)      // 8192 columns per batch
#define S   (B*SB)       // 262144 total columns
#define EPSF 1e-5f

#define FPS_BLOCKS 16        // 2 batches per block (interleaved chains)
#define TR_BLOCKS  (B*256)   // 8192 transpose tiles
#define PREP_BLOCKS 64

typedef __attribute__((ext_vector_type(8))) short short8;
typedef __attribute__((ext_vector_type(4))) float floatx4;

__device__ __forceinline__ float bf2f(unsigned short u) {
    return __uint_as_float(((unsigned)u) << 16);
}
__device__ __forceinline__ unsigned short f2bf(float f) {
    unsigned u = __float_as_uint(f);
    return (unsigned short)((u + 0x7FFFu + ((u >> 16) & 1u)) >> 16);
}

// wave64 max of nonneg-float bits via DPP (VALU pipe, no LDS crossbar), result uniform
__device__ __forceinline__ int wave_max_i32(int x) {
    int y;
    y = __builtin_amdgcn_update_dpp(0, x, 0x111, 0xf, 0xf, true); x = (y > x) ? y : x;
    y = __builtin_amdgcn_update_dpp(0, x, 0x112, 0xf, 0xf, true); x = (y > x) ? y : x;
    y = __builtin_amdgcn_update_dpp(0, x, 0x114, 0xf, 0xf, true); x = (y > x) ? y : x;
    y = __builtin_amdgcn_update_dpp(0, x, 0x118, 0xf, 0xf, true); x = (y > x) ? y : x;
    y = __builtin_amdgcn_update_dpp(0, x, 0x142, 0xa, 0xf, true); x = (y > x) ? y : x;
    y = __builtin_amdgcn_update_dpp(0, x, 0x143, 0xc, 0xf, true); x = (y > x) ? y : x;
    return __builtin_amdgcn_readlane(x, 63);
}
__device__ __forceinline__ unsigned wave_max_u32(unsigned x) {
    unsigned y;
    y = (unsigned)__builtin_amdgcn_update_dpp(0, (int)x, 0x111, 0xf, 0xf, true); x = (y > x) ? y : x;
    y = (unsigned)__builtin_amdgcn_update_dpp(0, (int)x, 0x112, 0xf, 0xf, true); x = (y > x) ? y : x;
    y = (unsigned)__builtin_amdgcn_update_dpp(0, (int)x, 0x114, 0xf, 0xf, true); x = (y > x) ? y : x;
    y = (unsigned)__builtin_amdgcn_update_dpp(0, (int)x, 0x118, 0xf, 0xf, true); x = (y > x) ? y : x;
    y = (unsigned)__builtin_amdgcn_update_dpp(0, (int)x, 0x142, 0xa, 0xf, true); x = (y > x) ? y : x;
    y = (unsigned)__builtin_amdgcn_update_dpp(0, (int)x, 0x143, 0xc, 0xf, true); x = (y > x) ? y : x;
    return (unsigned)__builtin_amdgcn_readlane((int)x, 63);
}

// ---------------- fused front: FPS (2 batches/block) + feat transpose(bf16) + weight prep(bf16) ----------------
__global__ __launch_bounds__(512) void fused_front_kernel(
        const float* __restrict__ seed, const float* __restrict__ xyz,
        const float* __restrict__ feat, const float* __restrict__ w1,
        const float* __restrict__ w2, const float* __restrict__ w3,
        unsigned short* __restrict__ featT, unsigned short* __restrict__ w1fb,
        unsigned short* __restrict__ w2b, unsigned short* __restrict__ w3b,
        float* __restrict__ stats, int* __restrict__ inds,
        float* __restrict__ out_newxyz, float* __restrict__ out_inds_f) {
    __shared__ float smem[6 * N];                 // 96 KB: 2 chains x (sx,sy,sz); transpose uses first 48KB
    __shared__ unsigned long long slot8[2][2][8]; // [parity][chain][wave]
    int bid = blockIdx.x;
    int t = threadIdx.x;

    if (bid >= FPS_BLOCKS) {
        int hb = bid - FPS_BLOCKS;
        if (hb < TR_BLOCKS) {
            // ---- transpose feat (B,C,N) fp32 -> featT (B,N,256) bf16, 32x128 tile ----
            float* ls = smem;
            int b2 = hb >> 8, rem = hb & 255;
            int ct = rem >> 5, jt = rem & 31;
            int c0 = ct * 32, j0 = jt * 128;
            const float* src = feat + (size_t)b2 * C * N;
            #pragma unroll
            for (int i = 0; i < 8; i++) {
                int lin = t + 512 * i;
                int jj = lin & 127, cc = lin >> 7;
                ls[cc * 129 + jj] = src[(size_t)(c0 + cc) * N + j0 + jj];
            }
            __syncthreads();
            int c8 = t & 3, jj = t >> 2;
            unsigned pk[4];
            #pragma unroll
            for (int q = 0; q < 4; q++) {
                float f0 = ls[(c8 * 8 + 2 * q) * 129 + jj];
                float f1 = ls[(c8 * 8 + 2 * q + 1) * 129 + jj];
                pk[q] = (unsigned)f2bf(f0) | ((unsigned)f2bf(f1) << 16);
            }
            *(uint4*)&featT[((size_t)b2 * N + j0 + jj) * 256 + c0 + c8 * 8] =
                make_uint4(pk[0], pk[1], pk[2], pk[3]);
        } else {
            // ---- prep: weights -> bf16 [o][k]; zero stats ----
            int i0 = (hb - TR_BLOCKS) * 512 + t;
            if (i0 < 256 * HID) { int o = i0 >> 8, k = i0 & 255; w1fb[i0] = f2bf(w1[o * CIN + 3 + k]); }
            if (i0 < HID * HID) { w2b[i0] = f2bf(w2[i0]); w3b[i0] = f2bf(w3[i0]); }
            if (i0 < 3 * 512) stats[i0] = 0.f;
        }
        return;
    }

    // ---- FPS for batches 2*bid and 2*bid+1: two independent chains interleaved ----
    int b0 = bid * 2;
    float* sx0 = smem;
    float* sy0 = smem + N;
    float* sz0 = smem + 2 * N;
    float* sx1 = smem + 3 * N;
    float* sy1 = smem + 4 * N;
    float* sz1 = smem + 5 * N;
    const float* sp0 = seed + (size_t)b0 * N * 3;
    const float* sp1 = seed + (size_t)(b0 + 1) * N * 3;
    float px0[8], py0[8], pz0[8], dl0[8];
    float px1[8], py1[8], pz1[8], dl1[8];
    #pragma unroll
    for (int u = 0; u < 8; u++) {
        int i = t + 512 * u;
        float x = sp0[i * 3 + 0], y = sp0[i * 3 + 1], z = sp0[i * 3 + 2];
        sx0[i] = x; sy0[i] = y; sz0[i] = z;
        px0[u] = x; py0[u] = y; pz0[u] = z; dl0[u] = 1e10f;
        x = sp1[i * 3 + 0]; y = sp1[i * 3 + 1]; z = sp1[i * 3 + 2];
        sx1[i] = x; sy1[i] = y; sz1[i] = z;
        px1[u] = x; py1[u] = y; pz1[u] = z; dl1[u] = 1e10f;
    }
    int* binds0 = inds + b0 * NP;
    int* binds1 = inds + (b0 + 1) * NP;
    if (t == 0) { binds0[0] = 0; binds1[0] = 0; }
    __syncthreads();
    int last0 = 0, last1 = 0;
    int lane = t & 63, w = t >> 6;
    for (int k = 1; k < NP; k++) {
        float lx0 = sx0[last0], ly0 = sy0[last0], lz0 = sz0[last0];
        float lx1 = sx1[last1], ly1 = sy1[last1], lz1 = sz1[last1];
        float bv0 = -1.f, bv1 = -1.f;
        int bi0 = 0, bi1 = 0;
        #pragma unroll
        for (int u = 0; u < 8; u++) {
            int i = t + 512 * u;
            // chain 0
            float dx = __fsub_rn(px0[u], lx0);
            float dy = __fsub_rn(py0[u], ly0);
            float dz = __fsub_rn(pz0[u], lz0);
            float d  = __fadd_rn(__fadd_rn(__fmul_rn(dx, dx), __fmul_rn(dy, dy)), __fmul_rn(dz, dz));
            float dm = fminf(dl0[u], d);
            dl0[u] = dm;
            if (dm > bv0) { bv0 = dm; bi0 = i; }   // i ascending in u -> strict > keeps min index
            // chain 1
            dx = __fsub_rn(px1[u], lx1);
            dy = __fsub_rn(py1[u], ly1);
            dz = __fsub_rn(pz1[u], lz1);
            d  = __fadd_rn(__fadd_rn(__fmul_rn(dx, dx), __fmul_rn(dy, dy)), __fmul_rn(dz, dz));
            dm = fminf(dl1[u], d);
            dl1[u] = dm;
            if (dm > bv1) { bv1 = dm; bi1 = i; }
        }
        // phase 1: wave max distance (nonneg f32 -> int compare valid), DPP — two chains interleave
        int wm0 = wave_max_i32(__float_as_int(bv0));
        int wm1 = wave_max_i32(__float_as_int(bv1));
        // phase 2: min index among lanes holding the max (unsigned max of ~idx; non-matching 0 loses)
        unsigned cand0 = (__float_as_int(bv0) == wm0) ? ~(unsigned)bi0 : 0u;
        unsigned cand1 = (__float_as_int(bv1) == wm1) ? ~(unsigned)bi1 : 0u;
        unsigned win0 = wave_max_u32(cand0);
        unsigned win1 = wave_max_u32(cand1);
        if (lane == 0) {
            int wbi0 = (int)(~win0);
            int wbi1 = (int)(~win1);
            slot8[k & 1][0][w] =
                (((unsigned long long)(unsigned)wm0) << 12) | (unsigned)(4095 - wbi0);
            slot8[k & 1][1][w] =
                (((unsigned long long)(unsigned)wm1) << 12) | (unsigned)(4095 - wbi1);
        }
        __syncthreads();
        unsigned long long best0 = slot8[k & 1][0][0];
        unsigned long long best1 = slot8[k & 1][1][0];
        #pragma unroll
        for (int j = 1; j < 8; j++) {
            unsigned long long v0 = slot8[k & 1][0][j];
            unsigned long long v1 = slot8[k & 1][1][j];
            if (v0 > best0) best0 = v0;
            if (v1 > best1) best1 = v1;
        }
        last0 = 4095 - (int)(best0 & 0xFFFull);
        last1 = 4095 - (int)(best1 & 0xFFFull);
        if (t == 0) { binds0[k] = last0; binds1[k] = last1; }
    }
    __syncthreads();
    {
        int p = t;   // 512 threads cover NP=512 per chain
        int j0 = binds0[p];
        const float* xb = xyz + ((size_t)b0 * N + j0) * 3;
        float* ob = out_newxyz + ((size_t)b0 * NP + p) * 3;
        ob[0] = xb[0]; ob[1] = xb[1]; ob[2] = xb[2];
        out_inds_f[b0 * NP + p] = (float)j0;
        int j1 = binds1[p];
        xb = xyz + ((size_t)(b0 + 1) * N + j1) * 3;
        ob = out_newxyz + ((size_t)(b0 + 1) * NP + p) * 3;
        ob[0] = xb[0]; ob[1] = xb[1]; ob[2] = xb[2];
        out_inds_f[(b0 + 1) * NP + p] = (float)j1;
    }
}

// ---------------- ball query: wave-parallel ballot scan, first NS by index ----------------
__global__ __launch_bounds__(256) void ballquery_kernel(const float* __restrict__ xyz,
        const float* __restrict__ newxyz, int* __restrict__ idx) {
    __shared__ float sx[N], sy[N], sz[N];
    int blk = blockIdx.x;
    int b   = blk >> 5;
    int q00 = (blk & 31) * 16;
    int t = threadIdx.x, lane = t & 63, w = t >> 6;
    const float* xb = xyz + (size_t)b * N * 3;
    for (int i = t; i < N; i += 256) { sx[i] = xb[i * 3]; sy[i] = xb[i * 3 + 1]; sz[i] = xb[i * 3 + 2]; }
    __syncthreads();
    for (int qi = 0; qi < 4; qi++) {
        int q = q00 + w * 4 + qi;
        const float* nq = newxyz + ((size_t)(b * NP + q)) * 3;
        float qx = nq[0], qy = nq[1], qz = nq[2];
        int* out = idx + ((size_t)(b * NP + q)) * NS;
        int cnt = 0, first = -1;
        for (int it = 0; it < 64; it++) {
            int j = it * 64 + lane;
            float dx = __fsub_rn(sx[j], qx);
            float dy = __fsub_rn(sy[j], qy);
            float dz = __fsub_rn(sz[j], qz);
            float d2 = __fadd_rn(__fadd_rn(__fmul_rn(dx, dx), __fmul_rn(dy, dy)), __fmul_rn(dz, dz));
            bool inb = d2 < 0.09f;
            unsigned long long m = __ballot(inb);
            if (m) {
                if (first < 0) first = it * 64 + __builtin_ctzll(m);
                if (inb) {
                    int r = cnt + __popcll(m & ((1ull << lane) - 1ull));
                    if (r < NS) out[r] = j;
                }
                cnt += __popcll(m);
                if (cnt >= NS) break;
            }
        }
        if (cnt < NS && lane >= cnt && lane < NS) out[lane] = first;
    }
}

// ---------------- GEMM1 (MFMA bf16): y1[s][o] = w1feat . gathered featT + xyz epilogue ----------------
__global__ __launch_bounds__(256) void gemm1_mfma(
        const unsigned short* __restrict__ w1fb, const float* __restrict__ w1raw,
        const unsigned short* __restrict__ featT, const float* __restrict__ newxyz,
        const float* __restrict__ xyz, const int* __restrict__ idx,
        unsigned short* __restrict__ y1) {
    __shared__ unsigned short Xs[128][136];       // [s][k] slab, reused as [s][o] out tile
    __shared__ float xn0[128], xn1[128], xn2[128];
    __shared__ int jl[128];
    int t = threadIdx.x;
    int s0 = blockIdx.x * 128;
    int b = s0 >> 13;
    if (t < 128) {
        int pn = (s0 & (SB - 1)) + t;
        int p = pn >> 4, n = pn & 15;
        int j = idx[((size_t)(b * NP + p)) * NS + n];
        jl[t] = j;
        const float* xb = xyz + ((size_t)(b * N + j)) * 3;
        const float* nq = newxyz + ((size_t)(b * NP + p)) * 3;
        xn0[t] = (xb[0] - nq[0]) / 0.3f;
        xn1[t] = (xb[1] - nq[1]) / 0.3f;
        xn2[t] = (xb[2] - nq[2]) / 0.3f;
    }
    __syncthreads();
    int lane = t & 63, w = t >> 6;
    int row16 = lane & 15, quad = lane >> 4;
    floatx4 acc[2][8];
    #pragma unroll
    for (int mt = 0; mt < 2; mt++)
        #pragma unroll
        for (int nt = 0; nt < 8; nt++)
            acc[mt][nt] = (floatx4){0.f, 0.f, 0.f, 0.f};
    int ss = t >> 1, hh = (t & 1) * 64;
    const unsigned short* grow = featT + ((size_t)b * N + jl[ss]) * 256 + hh;
    for (int slab = 0; slab < 2; slab++) {
        int k0 = slab * 128;
        {
            const uint4* src = (const uint4*)(grow + k0);
            #pragma unroll
            for (int i = 0; i < 8; i++)
                *(uint4*)&Xs[ss][hh + i * 8] = src[i];
        }
        __syncthreads();
        #pragma unroll
        for (int kk = 0; kk < 128; kk += 32) {
            short8 a0 = *(const short8*)&w1fb[(size_t)(w * 32 + row16) * 256 + k0 + kk + quad * 8];
            short8 a1 = *(const short8*)&w1fb[(size_t)(w * 32 + 16 + row16) * 256 + k0 + kk + quad * 8];
            #pragma unroll
            for (int nt = 0; nt < 8; nt++) {
                short8 bf = *(const short8*)&Xs[nt * 16 + row16][kk + quad * 8];
                acc[0][nt] = __builtin_amdgcn_mfma_f32_16x16x32_bf16(a0, bf, acc[0][nt], 0, 0, 0);
                acc[1][nt] = __builtin_amdgcn_mfma_f32_16x16x32_bf16(a1, bf, acc[1][nt], 0, 0, 0);
            }
        }
        __syncthreads();
    }
    // epilogue: + w1_xyz . xn (fp32), pack bf16, tile [s][o], coalesced global write
    float wa[8], wbv[8], wc[8];
    #pragma unroll
    for (int mt = 0; mt < 2; mt++)
        #pragma unroll
        for (int r = 0; r < 4; r++) {
            int o = w * 32 + mt * 16 + quad * 4 + r;
            const float* wr = w1raw + (size_t)o * CIN;
            wa[mt * 4 + r] = wr[0]; wbv[mt * 4 + r] = wr[1]; wc[mt * 4 + r] = wr[2];
        }
    float x0l[8], x1l[8], x2l[8];
    #pragma unroll
    for (int nt = 0; nt < 8; nt++) {
        int s = nt * 16 + row16;
        x0l[nt] = xn0[s]; x1l[nt] = xn1[s]; x2l[nt] = xn2[s];
    }
    #pragma unroll
    for (int mt = 0; mt < 2; mt++)
        #pragma unroll
        for (int nt = 0; nt < 8; nt++) {
            int s = nt * 16 + row16;
            int ob = w * 32 + mt * 16 + quad * 4;
            floatx4 a = acc[mt][nt];
            float v0 = a[0] + wa[mt*4+0]*x0l[nt] + wbv[mt*4+0]*x1l[nt] + wc[mt*4+0]*x2l[nt];
            float v1 = a[1] + wa[mt*4+1]*x0l[nt] + wbv[mt*4+1]*x1l[nt] + wc[mt*4+1]*x2l[nt];
            float v2 = a[2] + wa[mt*4+2]*x0l[nt] + wbv[mt*4+2]*x1l[nt] + wc[mt*4+2]*x2l[nt];
            float v3 = a[3] + wa[mt*4+3]*x0l[nt] + wbv[mt*4+3]*x1l[nt] + wc[mt*4+3]*x2l[nt];
            unsigned p0 = (unsigned)f2bf(v0) | ((unsigned)f2bf(v1) << 16);
            unsigned p1 = (unsigned)f2bf(v2) | ((unsigned)f2bf(v3) << 16);
            *(uint2*)&Xs[s][ob] = make_uint2(p0, p1);
        }
    __syncthreads();
    int c = t & 15, sr = t >> 4;
    #pragma unroll
    for (int i = 0; i < 8; i++) {
        int s = sr + 16 * i;
        uint4 v = *(const uint4*)&Xs[s][c * 8];
        *(uint4*)&y1[(size_t)(s0 + s) * 128 + c * 8] = v;
    }
}

// ---------------- GEMM2/3 (MFMA bf16): X = relu(affine(yprev)), Y[s][o] = W*X ----------------
__global__ __launch_bounds__(256) void gemm_bn_mfma(
        const unsigned short* __restrict__ wb16, const unsigned short* __restrict__ yprev,
        const float* __restrict__ statsPrev, unsigned short* __restrict__ yout) {
    __shared__ unsigned short Xs[128][136];
    __shared__ float ssc[128], ssh[128];
    int t = threadIdx.x;
    int s0 = blockIdx.x * 128;
    if (t < 128) { ssc[t] = statsPrev[256 + t]; ssh[t] = statsPrev[384 + t]; }
    __syncthreads();
    int ss = t >> 1, hh = (t & 1) * 64;
    {
        const uint4* src = (const uint4*)&yprev[(size_t)(s0 + ss) * 128 + hh];
        #pragma unroll
        for (int i = 0; i < 8; i++) {
            uint4 raw = src[i];
            int kb = hh + i * 8;
            float4 c0 = *(float4*)&ssc[kb];
            float4 c1 = *(float4*)&ssc[kb + 4];
            float4 h0 = *(float4*)&ssh[kb];
            float4 h1 = *(float4*)&ssh[kb + 4];
            float f0 = fmaxf(0.f, fmaf(bf2f((unsigned short)(raw.x & 0xFFFF)), c0.x, h0.x));
            float f1 = fmaxf(0.f, fmaf(bf2f((unsigned short)(raw.x >> 16)),    c0.y, h0.y));
            float f2 = fmaxf(0.f, fmaf(bf2f((unsigned short)(raw.y & 0xFFFF)), c0.z, h0.z));
            float f3 = fmaxf(0.f, fmaf(bf2f((unsigned short)(raw.y >> 16)),    c0.w, h0.w));
            float f4 = fmaxf(0.f, fmaf(bf2f((unsigned short)(raw.z & 0xFFFF)), c1.x, h1.x));
            float f5 = fmaxf(0.f, fmaf(bf2f((unsigned short)(raw.z >> 16)),    c1.y, h1.y));
            float f6 = fmaxf(0.f, fmaf(bf2f((unsigned short)(raw.w & 0xFFFF)), c1.z, h1.z));
            float f7 = fmaxf(0.f, fmaf(bf2f((unsigned short)(raw.w >> 16)),    c1.w, h1.w));
            unsigned o0 = (unsigned)f2bf(f0) | ((unsigned)f2bf(f1) << 16);
            unsigned o1 = (unsigned)f2bf(f2) | ((unsigned)f2bf(f3) << 16);
            unsigned o2 = (unsigned)f2bf(f4) | ((unsigned)f2bf(f5) << 16);
            unsigned o3 = (unsigned)f2bf(f6) | ((unsigned)f2bf(f7) << 16);
            *(uint4*)&Xs[ss][kb] = make_uint4(o0, o1, o2, o3);
        }
    }
    __syncthreads();
    int lane = t & 63, w = t >> 6;
    int row16 = lane & 15, quad = lane >> 4;
    floatx4 acc[2][8];
    #pragma unroll
    for (int mt = 0; mt < 2; mt++)
        #pragma unroll
        for (int nt = 0; nt < 8; nt++)
            acc[mt][nt] = (floatx4){0.f, 0.f, 0.f, 0.f};
    #pragma unroll
    for (int kk = 0; kk < 128; kk += 32) {
        short8 a0 = *(const short8*)&wb16[(size_t)(w * 32 + row16) * 128 + kk + quad * 8];
        short8 a1 = *(const short8*)&wb16[(size_t)(w * 32 + 16 + row16) * 128 + kk + quad * 8];
        #pragma unroll
        for (int nt = 0; nt < 8; nt++) {
            short8 bf = *(const short8*)&Xs[nt * 16 + row16][kk + quad * 8];
            acc[0][nt] = __builtin_amdgcn_mfma_f32_16x16x32_bf16(a0, bf, acc[0][nt], 0, 0, 0);
            acc[1][nt] = __builtin_amdgcn_mfma_f32_16x16x32_bf16(a1, bf, acc[1][nt], 0, 0, 0);
        }
    }
    __syncthreads();
    #pragma unroll
    for (int mt = 0; mt < 2; mt++)
        #pragma unroll
        for (int nt = 0; nt < 8; nt++) {
            int s = nt * 16 + row16;
            int ob = w * 32 + mt * 16 + quad * 4;
            floatx4 a = acc[mt][nt];
            unsigned p0 = (unsigned)f2bf(a[0]) | ((unsigned)f2bf(a[1]) << 16);
            unsigned p1 = (unsigned)f2bf(a[2]) | ((unsigned)f2bf(a[3]) << 16);
            *(uint2*)&Xs[s][ob] = make_uint2(p0, p1);
        }
    __syncthreads();
    int c = t & 15, sr = t >> 4;
    #pragma unroll
    for (int i = 0; i < 8; i++) {
        int s = sr + 16 * i;
        uint4 v = *(const uint4*)&Xs[s][c * 8];
        *(uint4*)&yout[(size_t)(s0 + s) * 128 + c * 8] = v;
    }
}

// ---------------- per-channel sum/sumsq over y[s][o] bf16 ----------------
__global__ __launch_bounds__(256) void stats_kernel(const unsigned short* __restrict__ y,
                                                    float* __restrict__ st) {
    __shared__ float ls[128], lq[128];
    int t = threadIdx.x;
    if (t < 128) { ls[t] = 0.f; lq[t] = 0.f; }
    __syncthreads();
    int c = t & 15, r0 = t >> 4;
    float s8[8] = {}, q8[8] = {};
    size_t base0 = (size_t)blockIdx.x * 512;
    for (int i = 0; i < 32; i++) {
        size_t s = base0 + r0 + (size_t)i * 16;
        uint4 v = *(const uint4*)&y[s * 128 + c * 8];
        unsigned ww[4] = {v.x, v.y, v.z, v.w};
        #pragma unroll
        for (int j = 0; j < 4; j++) {
            float f0 = bf2f((unsigned short)(ww[j] & 0xFFFF));
            float f1 = bf2f((unsigned short)(ww[j] >> 16));
            s8[2*j]   += f0; q8[2*j]   = fmaf(f0, f0, q8[2*j]);
            s8[2*j+1] += f1; q8[2*j+1] = fmaf(f1, f1, q8[2*j+1]);
        }
    }
    #pragma unroll
    for (int j = 0; j < 8; j++) {
        atomicAdd(&ls[c * 8 + j], s8[j]);
        atomicAdd(&lq[c * 8 + j], q8[j]);
    }
    __syncthreads();
    if (t < 128) { atomicAdd(&st[t], ls[t]); atomicAdd(&st[128 + t], lq[t]); }
}

// ---------------- BN params ----------------
__global__ void bnparam_kernel(float* __restrict__ stats, const float* __restrict__ g,
                               const float* __restrict__ be) {
    int o = threadIdx.x;
    float mean = stats[o] * (1.f / (float)S);
    float var  = stats[128 + o] * (1.f / (float)S) - mean * mean;
    float sc = g[o] / sqrtf(var + EPSF);
    stats[256 + o] = sc;
    stats[384 + o] = be[o] - mean * sc;
}

// ---------------- final: affine+relu+max over NS (y3 bf16 [s][o]) ----------------
__global__ __launch_bounds__(256) void maxpool_kernel(const unsigned short* __restrict__ y3,
        const float* __restrict__ st, float* __restrict__ out1) {
    int g = blockIdx.x * 256 + threadIdx.x;   // (b, oc, p), p fastest
    int p = g & 511;
    int oc = (g >> 9) & 15;
    int b = g >> 13;
    float sc[8], sh[8];
    #pragma unroll
    for (int j = 0; j < 8; j++) { sc[j] = st[256 + oc * 8 + j]; sh[j] = st[384 + oc * 8 + j]; }
    float m[8];
    #pragma unroll
    for (int j = 0; j < 8; j++) m[j] = 0.f;   // relu floor
    size_t base = ((size_t)(b * NP + p) * NS) * 128 + oc * 8;
    #pragma unroll
    for (int n = 0; n < 16; n++) {
        uint4 v = *(const uint4*)&y3[base + (size_t)n * 128];
        unsigned ww[4] = {v.x, v.y, v.z, v.w};
        #pragma unroll
        for (int j = 0; j < 4; j++) {
            m[2*j]   = fmaxf(m[2*j],   fmaf(bf2f((unsigned short)(ww[j] & 0xFFFF)), sc[2*j],   sh[2*j]));
            m[2*j+1] = fmaxf(m[2*j+1], fmaf(bf2f((unsigned short)(ww[j] >> 16)),    sc[2*j+1], sh[2*j+1]));
        }
    }
    #pragma unroll
    for (int j = 0; j < 8; j++)
        out1[((size_t)b * HID + oc * 8 + j) * NP + p] = m[j];
}

extern "C" void kernel_launch(void* const* d_in, const int* in_sizes, int n_in,
                              void* d_out, int out_size, void* d_ws, size_t ws_size,
                              hipStream_t stream) {
    const float* xyz  = (const float*)d_in[0];
    const float* feat = (const float*)d_in[1];
    const float* seed = (const float*)d_in[2];
    const float* w1 = (const float*)d_in[3];
    const float* g1 = (const float*)d_in[4];
    const float* be1 = (const float*)d_in[5];
    const float* w2 = (const float*)d_in[6];
    const float* g2 = (const float*)d_in[7];
    const float* be2 = (const float*)d_in[8];
    const float* w3 = (const float*)d_in[9];
    const float* g3 = (const float*)d_in[10];
    const float* be3 = (const float*)d_in[11];

    float* out_newxyz = (float*)d_out;                 // (B,NP,3)
    float* out_feat   = out_newxyz + B * NP * 3;       // (B,HID,NP)
    float* out_inds   = out_feat + B * HID * NP;       // (B,NP) as float

    float* stats = (float*)d_ws;                       // 3 x [sum|sq|sc|sh] x 128
    int*   inds  = (int*)(stats + 3 * 512);
    int*   idx   = inds + B * NP;
    unsigned short* w1fb  = (unsigned short*)(idx + (size_t)B * NP * NS);
    unsigned short* w2b   = w1fb + 256 * HID;
    unsigned short* w3b   = w2b + HID * HID;
    unsigned short* featT = w3b + HID * HID;           // B*N*256 bf16
    unsigned short* y1    = featT + (size_t)B * N * 256;   // S*128 bf16
    unsigned short* y2    = featT;                     // alias: featT dead after gemm1
    unsigned short* y3    = y1;                        // alias: y1 dead after gemm2

    size_t need = (size_t)(3 * 512) * 4 + (size_t)B * NP * 4 + (size_t)B * NP * NS * 4
                + (size_t)(256 * HID + 2 * HID * HID) * 2
                + 2ull * (size_t)B * N * 256 * 2;
    if (ws_size < need) return;

    fused_front_kernel<<<FPS_BLOCKS + TR_BLOCKS + PREP_BLOCKS, 512, 0, stream>>>(
        seed, xyz, feat, w1, w2, w3, featT, w1fb, w2b, w3b, stats,
        inds, out_newxyz, out_inds);
    ballquery_kernel<<<B * 32, 256, 0, stream>>>(xyz, out_newxyz, idx);
    gemm1_mfma<<<S / 128, 256, 0, stream>>>(w1fb, w1, featT, out_newxyz, xyz, idx, y1);
    stats_kernel<<<512, 256, 0, stream>>>(y1, stats);
    bnparam_kernel<<<1, HID, 0, stream>>>(stats, g1, be1);
    gemm_bn_mfma<<<S / 128, 256, 0, stream>>>(w2b, y1, stats, y2);
    stats_kernel<<<512, 256, 0, stream>>>(y2, stats + 512);
    bnparam_kernel<<<1, HID, 0, stream>>>(stats + 512, g2, be2);
    gemm_bn_mfma<<<S / 128, 256, 0, stream>>>(w3b, y2, stats + 512, y3);
    stats_kernel<<<512, 256, 0, stream>>>(y3, stats + 1024);
    bnparam_kernel<<<1, HID, 0, stream>>>(stats + 1024, g3, be3);
    maxpool_kernel<<<(B * 16 * NP) / 256, 256, 0, stream>>>(y3, stats + 1024, out_feat);
}

// Round 2
// 855.041 us; speedup vs baseline: 1.2195x; 1.2195x over previous
//
#include <hip/hip_runtime.h>
#include <cstdint>
#include <cstddef>

#define B   32
#define N   4096
#define NP  512
#define NS  16
#define C   256
#define CIN 259
#define HID 128
#define SB  (NP*NS)      // 8192 columns per batch
#define S   (B*SB)       // 262144 total columns
#define EPSF 1e-5f

#define FPS_BLOCKS 32
#define TR_BLOCKS  (B*256)   // 8192 transpose tiles
#define PREP_BLOCKS 64

typedef __attribute__((ext_vector_type(8))) short short8;
typedef __attribute__((ext_vector_type(4))) float floatx4;

__device__ __forceinline__ float bf2f(unsigned short u) {
    return __uint_as_float(((unsigned)u) << 16);
}
__device__ __forceinline__ unsigned short f2bf(float f) {
    unsigned u = __float_as_uint(f);
    return (unsigned short)((u + 0x7FFFu + ((u >> 16) & 1u)) >> 16);
}

// wave64 max of nonneg-float bits via DPP (VALU pipe, no LDS crossbar), result uniform
__device__ __forceinline__ int wave_max_i32(int x) {
    int y;
    y = __builtin_amdgcn_update_dpp(0, x, 0x111, 0xf, 0xf, true); x = (y > x) ? y : x;
    y = __builtin_amdgcn_update_dpp(0, x, 0x112, 0xf, 0xf, true); x = (y > x) ? y : x;
    y = __builtin_amdgcn_update_dpp(0, x, 0x114, 0xf, 0xf, true); x = (y > x) ? y : x;
    y = __builtin_amdgcn_update_dpp(0, x, 0x118, 0xf, 0xf, true); x = (y > x) ? y : x;
    y = __builtin_amdgcn_update_dpp(0, x, 0x142, 0xa, 0xf, true); x = (y > x) ? y : x;
    y = __builtin_amdgcn_update_dpp(0, x, 0x143, 0xc, 0xf, true); x = (y > x) ? y : x;
    return __builtin_amdgcn_readlane(x, 63);
}
__device__ __forceinline__ unsigned wave_max_u32(unsigned x) {
    unsigned y;
    y = (unsigned)__builtin_amdgcn_update_dpp(0, (int)x, 0x111, 0xf, 0xf, true); x = (y > x) ? y : x;
    y = (unsigned)__builtin_amdgcn_update_dpp(0, (int)x, 0x112, 0xf, 0xf, true); x = (y > x) ? y : x;
    y = (unsigned)__builtin_amdgcn_update_dpp(0, (int)x, 0x114, 0xf, 0xf, true); x = (y > x) ? y : x;
    y = (unsigned)__builtin_amdgcn_update_dpp(0, (int)x, 0x118, 0xf, 0xf, true); x = (y > x) ? y : x;
    y = (unsigned)__builtin_amdgcn_update_dpp(0, (int)x, 0x142, 0xa, 0xf, true); x = (y > x) ? y : x;
    y = (unsigned)__builtin_amdgcn_update_dpp(0, (int)x, 0x143, 0xc, 0xf, true); x = (y > x) ? y : x;
    return (unsigned)__builtin_amdgcn_readlane((int)x, 63);
}

__device__ __forceinline__ unsigned long long umax64(unsigned long long a, unsigned long long b) {
    return (b > a) ? b : a;
}

// ---------------- fused front: FPS + feat transpose(bf16) + weight prep(bf16) ----------------
__global__ __launch_bounds__(512) void fused_front_kernel(
        const float* __restrict__ seed, const float* __restrict__ xyz,
        const float* __restrict__ feat, const float* __restrict__ w1,
        const float* __restrict__ w2, const float* __restrict__ w3,
        unsigned short* __restrict__ featT, unsigned short* __restrict__ w1fb,
        unsigned short* __restrict__ w2b, unsigned short* __restrict__ w3b,
        float* __restrict__ stats, int* __restrict__ inds,
        float* __restrict__ out_newxyz, float* __restrict__ out_inds_f) {
    __shared__ float smem[3 * N];                       // 48 KB transpose tile
    __shared__ __align__(16) unsigned long long skey[2][8];   // [parity][wave] winner key
    __shared__ __align__(16) float4 scoord[2][8];             // [parity][wave] winner coords
    __shared__ int lhist[NP];                           // FPS selection history (LDS only)
    int bid = blockIdx.x;
    int t = threadIdx.x;

    if (bid >= FPS_BLOCKS) {
        int hb = bid - FPS_BLOCKS;
        if (hb < TR_BLOCKS) {
            // ---- transpose feat (B,C,N) fp32 -> featT (B,N,256) bf16, 32x128 tile ----
            float* ls = smem;
            int b2 = hb >> 8, rem = hb & 255;
            int ct = rem >> 5, jt = rem & 31;
            int c0 = ct * 32, j0 = jt * 128;
            const float* src = feat + (size_t)b2 * C * N;
            #pragma unroll
            for (int i = 0; i < 8; i++) {
                int lin = t + 512 * i;
                int jj = lin & 127, cc = lin >> 7;
                ls[cc * 129 + jj] = src[(size_t)(c0 + cc) * N + j0 + jj];
            }
            __syncthreads();
            int c8 = t & 3, jj = t >> 2;
            unsigned pk[4];
            #pragma unroll
            for (int q = 0; q < 4; q++) {
                float f0 = ls[(c8 * 8 + 2 * q) * 129 + jj];
                float f1 = ls[(c8 * 8 + 2 * q + 1) * 129 + jj];
                pk[q] = (unsigned)f2bf(f0) | ((unsigned)f2bf(f1) << 16);
            }
            *(uint4*)&featT[((size_t)b2 * N + j0 + jj) * 256 + c0 + c8 * 8] =
                make_uint4(pk[0], pk[1], pk[2], pk[3]);
        } else {
            // ---- prep: weights -> bf16 [o][k]; zero stats ----
            int i0 = (hb - TR_BLOCKS) * 512 + t;
            if (i0 < 256 * HID) { int o = i0 >> 8, k = i0 & 255; w1fb[i0] = f2bf(w1[o * CIN + 3 + k]); }
            if (i0 < HID * HID) { w2b[i0] = f2bf(w2[i0]); w3b[i0] = f2bf(w3[i0]); }
            if (i0 < 3 * 512) stats[i0] = 0.f;
        }
        return;
    }

    // ---- FPS for batch b = bid: zero global memory ops inside the loop ----
    int b = bid;
    const float* sp = seed + (size_t)b * N * 3;
    float px[8], py[8], pz[8], dloc[8];
    #pragma unroll
    for (int u = 0; u < 8; u++) {
        int i = t + 512 * u;
        px[u] = sp[i * 3 + 0]; py[u] = sp[i * 3 + 1]; pz[u] = sp[i * 3 + 2];
        dloc[u] = 1e10f;
    }
    if (t == 0) lhist[0] = 0;
    float lx = sp[0], ly = sp[1], lz = sp[2];   // first selected point = index 0
    int lane = t & 63, w = t >> 6;
    for (int k = 1; k < NP; k++) {
        float bv = -1.f; int bi = 0;
        float bx = 0.f, by = 0.f, bz = 0.f;
        #pragma unroll
        for (int u = 0; u < 8; u++) {
            int i = t + 512 * u;
            float dx = __fsub_rn(px[u], lx);
            float dy = __fsub_rn(py[u], ly);
            float dz = __fsub_rn(pz[u], lz);
            float d  = __fadd_rn(__fadd_rn(__fmul_rn(dx, dx), __fmul_rn(dy, dy)), __fmul_rn(dz, dz));
            float dm = fminf(dloc[u], d);
            dloc[u] = dm;
            bool bt = dm > bv;            // i ascending in u -> strict > keeps min index
            bv = bt ? dm : bv;
            bi = bt ? i : bi;
            bx = bt ? px[u] : bx;
            by = bt ? py[u] : by;
            bz = bt ? pz[u] : bz;
        }
        // phase 1: wave max distance (nonneg f32 -> int compare valid), DPP
        int wm = wave_max_i32(__float_as_int(bv));
        // phase 2: min index among lanes holding the max (unsigned max of ~idx; losers 0)
        unsigned cand = (__float_as_int(bv) == wm) ? ~(unsigned)bi : 0u;
        unsigned winv = wave_max_u32(cand);
        int wbi = (int)(~winv);
        int par = k & 1;
        // winner lane (lane == wbi&63 uniquely holds point wbi) writes key + coords
        if (lane == (wbi & 63)) {
            skey[par][w] = (((unsigned long long)(unsigned)wm) << 12) | (unsigned)(4095 - wbi);
            scoord[par][w] = make_float4(bx, by, bz, 0.f);
        }
        __syncthreads();
        // cross-wave: read 8 keys as 4x b128, 3-level tree, then one broadcast coord read
        const ulonglong2* kp = (const ulonglong2*)&skey[par][0];
        ulonglong2 q0 = kp[0], q1 = kp[1], q2 = kp[2], q3 = kp[3];
        unsigned long long a = umax64(q0.x, q0.y);
        unsigned long long c2 = umax64(q1.x, q1.y);
        unsigned long long e = umax64(q2.x, q2.y);
        unsigned long long g = umax64(q3.x, q3.y);
        unsigned long long h = umax64(umax64(a, c2), umax64(e, g));
        int gi = 4095 - (int)(h & 0xFFFull);
        int ws = (gi & 511) >> 6;
        float4 wc = scoord[par][ws];
        lx = wc.x; ly = wc.y; lz = wc.z;
        if (t == 0) lhist[k] = gi;
    }
    __syncthreads();
    {
        int p = t;   // 512 threads cover NP=512
        int j = lhist[p];
        const float* xb = xyz + ((size_t)b * N + j) * 3;
        float* ob = out_newxyz + ((size_t)b * NP + p) * 3;
        ob[0] = xb[0]; ob[1] = xb[1]; ob[2] = xb[2];
        out_inds_f[b * NP + p] = (float)j;
    }
}

// ---------------- ball query: wave-parallel ballot scan, first NS by index ----------------
__global__ __launch_bounds__(256) void ballquery_kernel(const float* __restrict__ xyz,
        const float* __restrict__ newxyz, int* __restrict__ idx) {
    __shared__ float sx[N], sy[N], sz[N];
    int blk = blockIdx.x;
    int b   = blk >> 5;
    int q00 = (blk & 31) * 16;
    int t = threadIdx.x, lane = t & 63, w = t >> 6;
    const float* xb = xyz + (size_t)b * N * 3;
    for (int i = t; i < N; i += 256) { sx[i] = xb[i * 3]; sy[i] = xb[i * 3 + 1]; sz[i] = xb[i * 3 + 2]; }
    __syncthreads();
    for (int qi = 0; qi < 4; qi++) {
        int q = q00 + w * 4 + qi;
        const float* nq = newxyz + ((size_t)(b * NP + q)) * 3;
        float qx = nq[0], qy = nq[1], qz = nq[2];
        int* out = idx + ((size_t)(b * NP + q)) * NS;
        int cnt = 0, first = -1;
        for (int it = 0; it < 64; it++) {
            int j = it * 64 + lane;
            float dx = __fsub_rn(sx[j], qx);
            float dy = __fsub_rn(sy[j], qy);
            float dz = __fsub_rn(sz[j], qz);
            float d2 = __fadd_rn(__fadd_rn(__fmul_rn(dx, dx), __fmul_rn(dy, dy)), __fmul_rn(dz, dz));
            bool inb = d2 < 0.09f;
            unsigned long long m = __ballot(inb);
            if (m) {
                if (first < 0) first = it * 64 + __builtin_ctzll(m);
                if (inb) {
                    int r = cnt + __popcll(m & ((1ull << lane) - 1ull));
                    if (r < NS) out[r] = j;
                }
                cnt += __popcll(m);
                if (cnt >= NS) break;
            }
        }
        if (cnt < NS && lane >= cnt && lane < NS) out[lane] = first;
    }
}

// ---------------- GEMM1 (MFMA bf16): y1[s][o] = w1feat . gathered featT + xyz epilogue ----------------
__global__ __launch_bounds__(256) void gemm1_mfma(
        const unsigned short* __restrict__ w1fb, const float* __restrict__ w1raw,
        const unsigned short* __restrict__ featT, const float* __restrict__ newxyz,
        const float* __restrict__ xyz, const int* __restrict__ idx,
        unsigned short* __restrict__ y1) {
    __shared__ unsigned short Xs[128][136];       // [s][k] slab, reused as [s][o] out tile
    __shared__ float xn0[128], xn1[128], xn2[128];
    __shared__ int jl[128];
    int t = threadIdx.x;
    int s0 = blockIdx.x * 128;
    int b = s0 >> 13;
    if (t < 128) {
        int pn = (s0 & (SB - 1)) + t;
        int p = pn >> 4, n = pn & 15;
        int j = idx[((size_t)(b * NP + p)) * NS + n];
        jl[t] = j;
        const float* xb = xyz + ((size_t)(b * N + j)) * 3;
        const float* nq = newxyz + ((size_t)(b * NP + p)) * 3;
        xn0[t] = (xb[0] - nq[0]) / 0.3f;
        xn1[t] = (xb[1] - nq[1]) / 0.3f;
        xn2[t] = (xb[2] - nq[2]) / 0.3f;
    }
    __syncthreads();
    int lane = t & 63, w = t >> 6;
    int row16 = lane & 15, quad = lane >> 4;
    floatx4 acc[2][8];
    #pragma unroll
    for (int mt = 0; mt < 2; mt++)
        #pragma unroll
        for (int nt = 0; nt < 8; nt++)
            acc[mt][nt] = (floatx4){0.f, 0.f, 0.f, 0.f};
    int ss = t >> 1, hh = (t & 1) * 64;
    const unsigned short* grow = featT + ((size_t)b * N + jl[ss]) * 256 + hh;
    for (int slab = 0; slab < 2; slab++) {
        int k0 = slab * 128;
        {
            const uint4* src = (const uint4*)(grow + k0);
            #pragma unroll
            for (int i = 0; i < 8; i++)
                *(uint4*)&Xs[ss][hh + i * 8] = src[i];
        }
        __syncthreads();
        #pragma unroll
        for (int kk = 0; kk < 128; kk += 32) {
            short8 a0 = *(const short8*)&w1fb[(size_t)(w * 32 + row16) * 256 + k0 + kk + quad * 8];
            short8 a1 = *(const short8*)&w1fb[(size_t)(w * 32 + 16 + row16) * 256 + k0 + kk + quad * 8];
            #pragma unroll
            for (int nt = 0; nt < 8; nt++) {
                short8 bf = *(const short8*)&Xs[nt * 16 + row16][kk + quad * 8];
                acc[0][nt] = __builtin_amdgcn_mfma_f32_16x16x32_bf16(a0, bf, acc[0][nt], 0, 0, 0);
                acc[1][nt] = __builtin_amdgcn_mfma_f32_16x16x32_bf16(a1, bf, acc[1][nt], 0, 0, 0);
            }
        }
        __syncthreads();
    }
    // epilogue: + w1_xyz . xn (fp32), pack bf16, tile [s][o], coalesced global write
    float wa[8], wbv[8], wc[8];
    #pragma unroll
    for (int mt = 0; mt < 2; mt++)
        #pragma unroll
        for (int r = 0; r < 4; r++) {
            int o = w * 32 + mt * 16 + quad * 4 + r;
            const float* wr = w1raw + (size_t)o * CIN;
            wa[mt * 4 + r] = wr[0]; wbv[mt * 4 + r] = wr[1]; wc[mt * 4 + r] = wr[2];
        }
    float x0l[8], x1l[8], x2l[8];
    #pragma unroll
    for (int nt = 0; nt < 8; nt++) {
        int s = nt * 16 + row16;
        x0l[nt] = xn0[s]; x1l[nt] = xn1[s]; x2l[nt] = xn2[s];
    }
    #pragma unroll
    for (int mt = 0; mt < 2; mt++)
        #pragma unroll
        for (int nt = 0; nt < 8; nt++) {
            int s = nt * 16 + row16;
            int ob = w * 32 + mt * 16 + quad * 4;
            floatx4 a = acc[mt][nt];
            float v0 = a[0] + wa[mt*4+0]*x0l[nt] + wbv[mt*4+0]*x1l[nt] + wc[mt*4+0]*x2l[nt];
            float v1 = a[1] + wa[mt*4+1]*x0l[nt] + wbv[mt*4+1]*x1l[nt] + wc[mt*4+1]*x2l[nt];
            float v2 = a[2] + wa[mt*4+2]*x0l[nt] + wbv[mt*4+2]*x1l[nt] + wc[mt*4+2]*x2l[nt];
            float v3 = a[3] + wa[mt*4+3]*x0l[nt] + wbv[mt*4+3]*x1l[nt] + wc[mt*4+3]*x2l[nt];
            unsigned p0 = (unsigned)f2bf(v0) | ((unsigned)f2bf(v1) << 16);
            unsigned p1 = (unsigned)f2bf(v2) | ((unsigned)f2bf(v3) << 16);
            *(uint2*)&Xs[s][ob] = make_uint2(p0, p1);
        }
    __syncthreads();
    int c = t & 15, sr = t >> 4;
    #pragma unroll
    for (int i = 0; i < 8; i++) {
        int s = sr + 16 * i;
        uint4 v = *(const uint4*)&Xs[s][c * 8];
        *(uint4*)&y1[(size_t)(s0 + s) * 128 + c * 8] = v;
    }
}

// ---------------- GEMM2/3 (MFMA bf16): X = relu(affine(yprev)), Y[s][o] = W*X ----------------
__global__ __launch_bounds__(256) void gemm_bn_mfma(
        const unsigned short* __restrict__ wb16, const unsigned short* __restrict__ yprev,
        const float* __restrict__ statsPrev, unsigned short* __restrict__ yout) {
    __shared__ unsigned short Xs[128][136];
    __shared__ float ssc[128], ssh[128];
    int t = threadIdx.x;
    int s0 = blockIdx.x * 128;
    if (t < 128) { ssc[t] = statsPrev[256 + t]; ssh[t] = statsPrev[384 + t]; }
    __syncthreads();
    int ss = t >> 1, hh = (t & 1) * 64;
    {
        const uint4* src = (const uint4*)&yprev[(size_t)(s0 + ss) * 128 + hh];
        #pragma unroll
        for (int i = 0; i < 8; i++) {
            uint4 raw = src[i];
            int kb = hh + i * 8;
            float4 c0 = *(float4*)&ssc[kb];
            float4 c1 = *(float4*)&ssc[kb + 4];
            float4 h0 = *(float4*)&ssh[kb];
            float4 h1 = *(float4*)&ssh[kb + 4];
            float f0 = fmaxf(0.f, fmaf(bf2f((unsigned short)(raw.x & 0xFFFF)), c0.x, h0.x));
            float f1 = fmaxf(0.f, fmaf(bf2f((unsigned short)(raw.x >> 16)),    c0.y, h0.y));
            float f2 = fmaxf(0.f, fmaf(bf2f((unsigned short)(raw.y & 0xFFFF)), c0.z, h0.z));
            float f3 = fmaxf(0.f, fmaf(bf2f((unsigned short)(raw.y >> 16)),    c0.w, h0.w));
            float f4 = fmaxf(0.f, fmaf(bf2f((unsigned short)(raw.z & 0xFFFF)), c1.x, h1.x));
            float f5 = fmaxf(0.f, fmaf(bf2f((unsigned short)(raw.z >> 16)),    c1.y, h1.y));
            float f6 = fmaxf(0.f, fmaf(bf2f((unsigned short)(raw.w & 0xFFFF)), c1.z, h1.z));
            float f7 = fmaxf(0.f, fmaf(bf2f((unsigned short)(raw.w >> 16)),    c1.w, h1.w));
            unsigned o0 = (unsigned)f2bf(f0) | ((unsigned)f2bf(f1) << 16);
            unsigned o1 = (unsigned)f2bf(f2) | ((unsigned)f2bf(f3) << 16);
            unsigned o2 = (unsigned)f2bf(f4) | ((unsigned)f2bf(f5) << 16);
            unsigned o3 = (unsigned)f2bf(f6) | ((unsigned)f2bf(f7) << 16);
            *(uint4*)&Xs[ss][kb] = make_uint4(o0, o1, o2, o3);
        }
    }
    __syncthreads();
    int lane = t & 63, w = t >> 6;
    int row16 = lane & 15, quad = lane >> 4;
    floatx4 acc[2][8];
    #pragma unroll
    for (int mt = 0; mt < 2; mt++)
        #pragma unroll
        for (int nt = 0; nt < 8; nt++)
            acc[mt][nt] = (floatx4){0.f, 0.f, 0.f, 0.f};
    #pragma unroll
    for (int kk = 0; kk < 128; kk += 32) {
        short8 a0 = *(const short8*)&wb16[(size_t)(w * 32 + row16) * 128 + kk + quad * 8];
        short8 a1 = *(const short8*)&wb16[(size_t)(w * 32 + 16 + row16) * 128 + kk + quad * 8];
        #pragma unroll
        for (int nt = 0; nt < 8; nt++) {
            short8 bf = *(const short8*)&Xs[nt * 16 + row16][kk + quad * 8];
            acc[0][nt] = __builtin_amdgcn_mfma_f32_16x16x32_bf16(a0, bf, acc[0][nt], 0, 0, 0);
            acc[1][nt] = __builtin_amdgcn_mfma_f32_16x16x32_bf16(a1, bf, acc[1][nt], 0, 0, 0);
        }
    }
    __syncthreads();
    #pragma unroll
    for (int mt = 0; mt < 2; mt++)
        #pragma unroll
        for (int nt = 0; nt < 8; nt++) {
            int s = nt * 16 + row16;
            int ob = w * 32 + mt * 16 + quad * 4;
            floatx4 a = acc[mt][nt];
            unsigned p0 = (unsigned)f2bf(a[0]) | ((unsigned)f2bf(a[1]) << 16);
            unsigned p1 = (unsigned)f2bf(a[2]) | ((unsigned)f2bf(a[3]) << 16);
            *(uint2*)&Xs[s][ob] = make_uint2(p0, p1);
        }
    __syncthreads();
    int c = t & 15, sr = t >> 4;
    #pragma unroll
    for (int i = 0; i < 8; i++) {
        int s = sr + 16 * i;
        uint4 v = *(const uint4*)&Xs[s][c * 8];
        *(uint4*)&yout[(size_t)(s0 + s) * 128 + c * 8] = v;
    }
}

// ---------------- per-channel sum/sumsq over y[s][o] bf16 ----------------
__global__ __launch_bounds__(256) void stats_kernel(const unsigned short* __restrict__ y,
                                                    float* __restrict__ st) {
    __shared__ float ls[128], lq[128];
    int t = threadIdx.x;
    if (t < 128) { ls[t] = 0.f; lq[t] = 0.f; }
    __syncthreads();
    int c = t & 15, r0 = t >> 4;
    float s8[8] = {}, q8[8] = {};
    size_t base0 = (size_t)blockIdx.x * 512;
    for (int i = 0; i < 32; i++) {
        size_t s = base0 + r0 + (size_t)i * 16;
        uint4 v = *(const uint4*)&y[s * 128 + c * 8];
        unsigned ww[4] = {v.x, v.y, v.z, v.w};
        #pragma unroll
        for (int j = 0; j < 4; j++) {
            float f0 = bf2f((unsigned short)(ww[j] & 0xFFFF));
            float f1 = bf2f((unsigned short)(ww[j] >> 16));
            s8[2*j]   += f0; q8[2*j]   = fmaf(f0, f0, q8[2*j]);
            s8[2*j+1] += f1; q8[2*j+1] = fmaf(f1, f1, q8[2*j+1]);
        }
    }
    #pragma unroll
    for (int j = 0; j < 8; j++) {
        atomicAdd(&ls[c * 8 + j], s8[j]);
        atomicAdd(&lq[c * 8 + j], q8[j]);
    }
    __syncthreads();
    if (t < 128) { atomicAdd(&st[t], ls[t]); atomicAdd(&st[128 + t], lq[t]); }
}

// ---------------- BN params ----------------
__global__ void bnparam_kernel(float* __restrict__ stats, const float* __restrict__ g,
                               const float* __restrict__ be) {
    int o = threadIdx.x;
    float mean = stats[o] * (1.f / (float)S);
    float var  = stats[128 + o] * (1.f / (float)S) - mean * mean;
    float sc = g[o] / sqrtf(var + EPSF);
    stats[256 + o] = sc;
    stats[384 + o] = be[o] - mean * sc;
}

// ---------------- final: affine+relu+max over NS (y3 bf16 [s][o]) ----------------
__global__ __launch_bounds__(256) void maxpool_kernel(const unsigned short* __restrict__ y3,
        const float* __restrict__ st, float* __restrict__ out1) {
    int g = blockIdx.x * 256 + threadIdx.x;   // (b, oc, p), p fastest
    int p = g & 511;
    int oc = (g >> 9) & 15;
    int b = g >> 13;
    float sc[8], sh[8];
    #pragma unroll
    for (int j = 0; j < 8; j++) { sc[j] = st[256 + oc * 8 + j]; sh[j] = st[384 + oc * 8 + j]; }
    float m[8];
    #pragma unroll
    for (int j = 0; j < 8; j++) m[j] = 0.f;   // relu floor
    size_t base = ((size_t)(b * NP + p) * NS) * 128 + oc * 8;
    #pragma unroll
    for (int n = 0; n < 16; n++) {
        uint4 v = *(const uint4*)&y3[base + (size_t)n * 128];
        unsigned ww[4] = {v.x, v.y, v.z, v.w};
        #pragma unroll
        for (int j = 0; j < 4; j++) {
            m[2*j]   = fmaxf(m[2*j],   fmaf(bf2f((unsigned short)(ww[j] & 0xFFFF)), sc[2*j],   sh[2*j]));
            m[2*j+1] = fmaxf(m[2*j+1], fmaf(bf2f((unsigned short)(ww[j] >> 16)),    sc[2*j+1], sh[2*j+1]));
        }
    }
    #pragma unroll
    for (int j = 0; j < 8; j++)
        out1[((size_t)b * HID + oc * 8 + j) * NP + p] = m[j];
}

extern "C" void kernel_launch(void* const* d_in, const int* in_sizes, int n_in,
                              void* d_out, int out_size, void* d_ws, size_t ws_size,
                              hipStream_t stream) {
    const float* xyz  = (const float*)d_in[0];
    const float* feat = (const float*)d_in[1];
    const float* seed = (const float*)d_in[2];
    const float* w1 = (const float*)d_in[3];
    const float* g1 = (const float*)d_in[4];
    const float* be1 = (const float*)d_in[5];
    const float* w2 = (const float*)d_in[6];
    const float* g2 = (const float*)d_in[7];
    const float* be2 = (const float*)d_in[8];
    const float* w3 = (const float*)d_in[9];
    const float* g3 = (const float*)d_in[10];
    const float* be3 = (const float*)d_in[11];

    float* out_newxyz = (float*)d_out;                 // (B,NP,3)
    float* out_feat   = out_newxyz + B * NP * 3;       // (B,HID,NP)
    float* out_inds   = out_feat + B * HID * NP;       // (B,NP) as float

    float* stats = (float*)d_ws;                       // 3 x [sum|sq|sc|sh] x 128
    int*   inds  = (int*)(stats + 3 * 512);
    int*   idx   = inds + B * NP;
    unsigned short* w1fb  = (unsigned short*)(idx + (size_t)B * NP * NS);
    unsigned short* w2b   = w1fb + 256 * HID;
    unsigned short* w3b   = w2b + HID * HID;
    unsigned short* featT = w3b + HID * HID;           // B*N*256 bf16
    unsigned short* y1    = featT + (size_t)B * N * 256;   // S*128 bf16
    unsigned short* y2    = featT;                     // alias: featT dead after gemm1
    unsigned short* y3    = y1;                        // alias: y1 dead after gemm2

    size_t need = (size_t)(3 * 512) * 4 + (size_t)B * NP * 4 + (size_t)B * NP * NS * 4
                + (size_t)(256 * HID + 2 * HID * HID) * 2
                + 2ull * (size_t)B * N * 256 * 2;
    if (ws_size < need) return;

    fused_front_kernel<<<FPS_BLOCKS + TR_BLOCKS + PREP_BLOCKS, 512, 0, stream>>>(
        seed, xyz, feat, w1, w2, w3, featT, w1fb, w2b, w3b, stats,
        inds, out_newxyz, out_inds);
    ballquery_kernel<<<B * 32, 256, 0, stream>>>(xyz, out_newxyz, idx);
    gemm1_mfma<<<S / 128, 256, 0, stream>>>(w1fb, w1, featT, out_newxyz, xyz, idx, y1);
    stats_kernel<<<512, 256, 0, stream>>>(y1, stats);
    bnparam_kernel<<<1, HID, 0, stream>>>(stats, g1, be1);
    gemm_bn_mfma<<<S / 128, 256, 0, stream>>>(w2b, y1, stats, y2);
    stats_kernel<<<512, 256, 0, stream>>>(y2, stats + 512);
    bnparam_kernel<<<1, HID, 0, stream>>>(stats + 512, g2, be2);
    gemm_bn_mfma<<<S / 128, 256, 0, stream>>>(w3b, y2, stats + 512, y3);
    stats_kernel<<<512, 256, 0, stream>>>(y3, stats + 1024);
    bnparam_kernel<<<1, HID, 0, stream>>>(stats + 1024, g3, be3);
    maxpool_kernel<<<(B * 16 * NP) / 256, 256, 0, stream>>>(y3, stats + 1024, out_feat);
}